// Round 1
// baseline (212.731 us; speedup 1.0000x reference)
//
#include <hip/hip_runtime.h>
#include <hip/hip_bf16.h>

#define N_ROWS 16384
#define D_COLS 2048
#define NUM_LABELS 1024
#define NUM_CAMS 8
#define NUM_SEG (NUM_LABELS * NUM_CAMS)   // 8192
#define MAXPER 64                          // list capacity per segment
#define GSEG 8                             // segments per block
#define NUM_GROUPS (NUM_SEG / GSEG)        // 1024
#define NUM_BLOCKS (NUM_GROUPS * 2)        // 2048 blocks: (group, column-half) -> 8/CU, ALL resident
#define FAST_R 8                           // register-cached rows per segment (P(cnt>8) ~ 3e-4/seg)
#define IDX_LDS 12                         // indices staged in LDS per segment
#define F4_PER_ROW (D_COLS / 4)            // 512 float4 per row

// ---------------- kernel 1: build per-segment row lists (+ zero the output accumulator) ----------------
__global__ void build_lists_kernel(const int* __restrict__ labels,
                                   const int* __restrict__ cams,
                                   int* __restrict__ counts,
                                   int* __restrict__ lists,
                                   float* __restrict__ out) {
    int i = blockIdx.x * blockDim.x + threadIdx.x;
    if (i == 0) out[0] = 0.0f;   // stream-ordered before group_loss's atomicAdds
    if (i < N_ROWS) {
        int seg = labels[i] * NUM_CAMS + cams[i];
        int pos = atomicAdd(&counts[seg], 1);
        if (pos < MAXPER) lists[seg * MAXPER + pos] = i;
    }
}

__device__ __forceinline__ float smooth_l1(float d) {
    float ad = fabsf(d);
    return ad < 1.0f ? 0.5f * d * d : ad - 0.5f;
}

// ---------------- kernel 2: one block per (8 segments, column-half) ----------------
// 2048 blocks = 8/CU, all co-resident: NO sequential block generations.
// Phase 0: stage counts + first 12 row indices per segment into LDS (one
// coalesced load, one barrier). Then loop segments: <=FAST_R predicated
// parallel loads cached in registers (single global pass, 134 MB total),
// mean, SmoothL1 from registers. Segment loop kept ROLLED so VGPR stays
// under 64 at __launch_bounds__(256,8); overlap comes from 8 resident blocks.
// Final reduction fused: one scaled atomicAdd per block into out[0]
// (replaces the partials buffer + reduce_kernel dispatch).
__global__ __launch_bounds__(256, 8) void group_loss_kernel(const float* __restrict__ feats,
                                                            const int* __restrict__ counts,
                                                            const int* __restrict__ lists,
                                                            float* __restrict__ out) {
    int bid  = blockIdx.x;
    int grp  = bid >> 1;
    int half = bid & 1;
    int tid  = threadIdx.x;
    int seg0 = grp * GSEG;

    __shared__ int   scnt[GSEG];
    __shared__ int   sidx[GSEG][IDX_LDS];
    __shared__ float wsum[4];

    // phase 0: metadata -> LDS (threads 0..7 counts, 8..103 indices)
    if (tid < GSEG) {
        scnt[tid] = counts[seg0 + tid];
    } else if (tid < GSEG + GSEG * IDX_LDS) {
        int j = tid - GSEG;
        int s = j / IDX_LDS;
        int r = j - s * IDX_LDS;
        // may read unwritten (poison) list slots; masked by cnt before any use
        sidx[s][r] = lists[(seg0 + s) * MAXPER + r];
    }
    __syncthreads();

    const float4* base = (const float4*)feats + (half * 256 + tid);
    float loss = 0.0f;

#pragma unroll 1   // keep rolled: VGPR budget; cross-block residency provides overlap
    for (int s = 0; s < GSEG; ++s) {
        int cnt  = scnt[s];                        // block-uniform
        int rows = cnt < FAST_R ? cnt : FAST_R;

        // predicated parallel loads, cached in registers (zeros where unused)
        float4 v[FAST_R];
#pragma unroll
        for (int r = 0; r < FAST_R; ++r) {
            v[r] = make_float4(0.f, 0.f, 0.f, 0.f);
            if (r < rows)
                v[r] = base[(size_t)sidx[s][r] * F4_PER_ROW];
        }

        float mx = 0.f, my = 0.f, mz = 0.f, mw = 0.f;
#pragma unroll
        for (int r = 0; r < FAST_R; ++r) {
            mx += v[r].x; my += v[r].y; mz += v[r].z; mw += v[r].w;
        }

        if (cnt > FAST_R) {   // rare tail (cnt>8): stream-add
            for (int r = FAST_R; r < cnt && r < IDX_LDS; ++r) {
                float4 a = base[(size_t)sidx[s][r] * F4_PER_ROW];
                mx += a.x; my += a.y; mz += a.z; mw += a.w;
            }
            for (int r = IDX_LDS; r < cnt && r < MAXPER; ++r) {
                float4 a = base[(size_t)lists[(seg0 + s) * MAXPER + r] * F4_PER_ROW];
                mx += a.x; my += a.y; mz += a.z; mw += a.w;
            }
        }

        float inv = 1.0f / (float)(cnt > 0 ? cnt : 1);
        mx *= inv; my *= inv; mz *= inv; mw *= inv;

        // loss from cached registers (no reload on the fast path)
#pragma unroll
        for (int r = 0; r < FAST_R; ++r) {
            if (r < rows)
                loss += smooth_l1(v[r].x - mx) + smooth_l1(v[r].y - my)
                      + smooth_l1(v[r].z - mz) + smooth_l1(v[r].w - mw);
        }
        if (cnt > FAST_R) {   // rare tail: re-stream (L2-hot)
            for (int r = FAST_R; r < cnt && r < IDX_LDS; ++r) {
                float4 a = base[(size_t)sidx[s][r] * F4_PER_ROW];
                loss += smooth_l1(a.x - mx) + smooth_l1(a.y - my)
                      + smooth_l1(a.z - mz) + smooth_l1(a.w - mw);
            }
            for (int r = IDX_LDS; r < cnt && r < MAXPER; ++r) {
                float4 a = base[(size_t)lists[(seg0 + s) * MAXPER + r] * F4_PER_ROW];
                loss += smooth_l1(a.x - mx) + smooth_l1(a.y - my)
                      + smooth_l1(a.z - mz) + smooth_l1(a.w - mw);
            }
        }
    }

    // block reduction: wave64 shuffle then LDS across 4 waves, then one atomic
    for (int o = 32; o > 0; o >>= 1)
        loss += __shfl_down(loss, o, 64);

    int lane = tid & 63;
    int wid  = tid >> 6;
    if (lane == 0) wsum[wid] = loss;
    __syncthreads();
    if (tid == 0) {
        float t = (wsum[0] + wsum[1] + wsum[2] + wsum[3])
                * (1.0f / ((float)N_ROWS * (float)D_COLS));
        atomicAdd(out, t);   // 2048 adds of ~1.7e-4 -> ~1e-7 rel. error
    }
}

extern "C" void kernel_launch(void* const* d_in, const int* in_sizes, int n_in,
                              void* d_out, int out_size, void* d_ws, size_t ws_size,
                              hipStream_t stream) {
    const float* feats = (const float*)d_in[0];
    const int* labels  = (const int*)d_in[1];
    const int* cams    = (const int*)d_in[2];
    float* out = (float*)d_out;

    // ws layout: counts[NUM_SEG] | lists[NUM_SEG*MAXPER]
    int* counts = (int*)d_ws;
    int* lists  = counts + NUM_SEG;

    hipMemsetAsync(counts, 0, NUM_SEG * sizeof(int), stream);   // only counts need zeroing

    build_lists_kernel<<<(N_ROWS + 255) / 256, 256, 0, stream>>>(labels, cams, counts, lists, out);
    group_loss_kernel<<<NUM_BLOCKS, 256, 0, stream>>>(feats, counts, lists, out);
}